// Round 5
// baseline (863.908 us; speedup 1.0000x reference)
//
#include <hip/hip_runtime.h>

#define P_PIX 22500
#define HB 61
#define HSP 16           // pixel splits for hist
#define PPB 1408         // pixels per hist block (HSP*PPB >= P_PIX)
#define NCHK 11          // 128-px chunks per hist block

typedef float f32x4 __attribute__((ext_vector_type(4)));
typedef _Float16 f16x8 __attribute__((ext_vector_type(8)));

// ---------------------------------------------------------------------------
// MFMA RGB-uv soft histogram (fp16 fragments).  grid (48, HSP), block 256.
// hist[u,v] = sum_p (ku[p,u]*w[p]) * kv[p,v]  == GEMM M=N=64, K=P.
// ---------------------------------------------------------------------------
__global__ __launch_bounds__(256) void hist_mfma(
    const float* __restrict__ img, const float* __restrict__ su,
    const float* __restrict__ sv, const float* __restrict__ cw,
    const float* __restrict__ msc, float* __restrict__ hist)
{
    const int bc = blockIdx.x;
    const int b = bc / 3, c = bc % 3;
    const int split = blockIdx.y;
    const int tid  = threadIdx.x;
    const int w    = tid >> 6;      // wave id -> owns u-strip [16w,16w+16)
    const int lane = tid & 63;
    const int quad = lane >> 4;
    const int mr   = lane & 15;

    __shared__ __align__(16) _Float16 A_lds[8192];   // [pg(16)][u(64)][j(8)]
    __shared__ __align__(16) _Float16 B_lds[8192];
    __shared__ float suu[128], svv[128], sww[128];

    const float sig_u = su[c], sig_v = sv[c];
    const float inv_su2 = 1.f / (sig_u * sig_u);
    const float inv_sv2 = 1.f / (sig_v * sig_v);
    const float cwc = cw[c];

    const bool hasM = (msc != nullptr);
    float m00=0,m01=0,m02=0,m10=0,m11=0,m12=0,m20=0,m21=0,m22=0;
    if (hasM) {
        const float* mp = msc + b * 9;
        m00=mp[0]; m01=mp[1]; m02=mp[2];
        m10=mp[3]; m11=mp[4]; m12=mp[5];
        m20=mp[6]; m21=mp[7]; m22=mp[8];
    }

    const int p0   = split * PPB;
    const int pend = min(p0 + PPB, P_PIX);

    f32x4 acc[4];
#pragma unroll
    for (int nt = 0; nt < 4; ++nt) acc[nt] = (f32x4){0.f, 0.f, 0.f, 0.f};

    for (int chunk = 0; chunk < NCHK; ++chunk) {
        __syncthreads();
        if (tid < 128) {
            int px = p0 + chunk * 128 + tid;
            float u = 0.f, v = 0.f, wgt = 0.f;
            if (px < pend) {
                const float* ip = img + (size_t)b * 3 * P_PIX + px;
                float r = ip[0], g = ip[P_PIX], bl = ip[2 * P_PIX];
                if (hasM) {
                    float r2 = m00 * r + m01 * g + m02 * bl;
                    float g2 = m10 * r + m11 * g + m12 * bl;
                    float b2 = m20 * r + m21 * g + m22 * bl;
                    r = r2; g = g2; bl = b2;
                }
                r  = fminf(fmaxf(r, 0.f), 1.f);
                g  = fminf(fmaxf(g, 0.f), 1.f);
                bl = fminf(fmaxf(bl, 0.f), 1.f);
                float Iy = sqrtf(r * r + g * g + bl * bl);
                float lr = __logf(r + 1e-6f);
                float lg = __logf(g + 1e-6f);
                float lb = __logf(bl + 1e-6f);
                if (c == 0)      { u = lr - lg; v = lr - lb; }
                else if (c == 1) { u = lg - lr; v = lg - lb; }
                else             { u = lb - lr; v = lb - lg; }
                wgt = Iy * cwc;
            }
            suu[tid] = u; svv[tid] = v; sww[tid] = wgt;
        }
        __syncthreads();
#pragma unroll
        for (int r = 0; r < 4; ++r) {
            int idx = tid + 256 * r;
            int u  = idx & 63;
            int pg = idx >> 6;
            float ub = -3.f + 0.1f * (float)u;
            const float* up = &suu[pg * 8];
            const float* wp = &sww[pg * 8];
            f16x8 av;
#pragma unroll
            for (int j = 0; j < 8; ++j) {
                float du = up[j] - ub;
                av[j] = (_Float16)(__expf(-du * du * inv_su2) * wp[j]);
            }
            *(f16x8*)&A_lds[(pg * 64 + u) * 8] = av;
        }
#pragma unroll
        for (int r = 0; r < 4; ++r) {
            int idx = tid + 256 * r;
            int u  = idx & 63;
            int pg = idx >> 6;
            float ub = -3.f + 0.1f * (float)u;
            const float* vp = &svv[pg * 8];
            f16x8 bv;
#pragma unroll
            for (int j = 0; j < 8; ++j) {
                float dv = vp[j] - ub;
                bv[j] = (_Float16)__expf(-dv * dv * inv_sv2);
            }
            *(f16x8*)&B_lds[(pg * 64 + u) * 8] = bv;
        }
        __syncthreads();
#pragma unroll
        for (int kk = 0; kk < 4; ++kk) {
            int pgq = kk * 4 + quad;
            f16x8 av = *(const f16x8*)&A_lds[(pgq * 64 + w * 16 + mr) * 8];
#pragma unroll
            for (int nt = 0; nt < 4; ++nt) {
                f16x8 bv = *(const f16x8*)&B_lds[(pgq * 64 + nt * 16 + mr) * 8];
                acc[nt] = __builtin_amdgcn_mfma_f32_16x16x32_f16(av, bv, acc[nt], 0, 0, 0);
            }
        }
    }

    float* hp = hist + (size_t)bc * HB * HB;
#pragma unroll
    for (int nt = 0; nt < 4; ++nt) {
        int v = nt * 16 + mr;
        if (v >= HB) continue;
#pragma unroll
        for (int r = 0; r < 4; ++r) {
            int u = w * 16 + quad * 4 + r;
            if (u < HB) atomicAdd(&hp[u * HB + v], acc[nt][r]);
        }
    }
}

// ---------------------------------------------------------------------------
// Per-batch normalization: hist /= (sum + 1e-6).  grid 16, block 256.
// ---------------------------------------------------------------------------
__global__ __launch_bounds__(256) void norm_hist(float* __restrict__ hist)
{
    const int b = blockIdx.x;
    float* hp = hist + (size_t)b * 3 * HB * HB;
    const int N = 3 * HB * HB;
    float s = 0.f;
    for (int i = threadIdx.x; i < N; i += 256) s += hp[i];
    __shared__ float red[4];
    for (int off = 32; off; off >>= 1) s += __shfl_down(s, off, 64);
    if ((threadIdx.x & 63) == 0) red[threadIdx.x >> 6] = s;
    __syncthreads();
    float inv = 1.f / (red[0] + red[1] + red[2] + red[3] + 1e-6f);
    for (int i = threadIdx.x; i < N; i += 256) hp[i] *= inv;
}

// ---------------------------------------------------------------------------
// conv1: direct fp32 conv + bias + ReLU, writes f16 output.
// ---------------------------------------------------------------------------
template<int CIN, int COUT, int K, int S, int IN, int OUT, int CPB, int CCH, int NSP>
__global__ __launch_bounds__(256) void conv_relu(
    const float* __restrict__ in, const float* __restrict__ wt,
    const float* __restrict__ bias, _Float16* __restrict__ out)
{
    constexpr int NCH = CIN / CCH;
    constexpr int OSZ = OUT * OUT;
    const int b = blockIdx.x;
    const int co0 = blockIdx.y * CPB;
    const int tid = threadIdx.x;

    __shared__ __align__(16) float sIn[CCH * IN * IN];
    __shared__ __align__(16) float sW[CCH * K * K * CPB];
    __shared__ float sB[CPB];
    if (tid < CPB) sB[tid] = bias[co0 + tid];

    float acc[NSP][CPB];
#pragma unroll
    for (int i = 0; i < NSP; ++i)
#pragma unroll
        for (int j = 0; j < CPB; ++j) acc[i][j] = 0.f;

    for (int ch = 0; ch < NCH; ++ch) {
        const float* gin = in + ((size_t)b * CIN + ch * CCH) * (IN * IN);
        for (int i = tid; i < CCH * IN * IN; i += 256) sIn[i] = gin[i];
        const float* gwt = wt + (size_t)co0 * CIN * K * K + (size_t)ch * CCH * K * K;
        for (int i = tid; i < CCH * K * K * CPB; i += 256) {
            int co = i % CPB;
            int r  = i / CPB;
            sW[i] = gwt[(size_t)co * CIN * K * K + r];
        }
        __syncthreads();
#pragma unroll
        for (int isp = 0; isp < NSP; ++isp) {
            int sp = tid + isp * 256;
            if (sp < OSZ) {
                int oh = sp / OUT, ow = sp % OUT;
                const float* ibase = &sIn[(oh * S) * IN + ow * S];
                for (int ci = 0; ci < CCH; ++ci) {
#pragma unroll
                    for (int kh = 0; kh < K; ++kh) {
#pragma unroll
                        for (int kw = 0; kw < K; ++kw) {
                            float x = ibase[ci * IN * IN + kh * IN + kw];
                            const float4* w4 =
                                (const float4*)&sW[(ci * K * K + kh * K + kw) * CPB];
#pragma unroll
                            for (int c4 = 0; c4 < CPB / 4; ++c4) {
                                float4 wv = w4[c4];
                                acc[isp][c4 * 4 + 0] = fmaf(x, wv.x, acc[isp][c4 * 4 + 0]);
                                acc[isp][c4 * 4 + 1] = fmaf(x, wv.y, acc[isp][c4 * 4 + 1]);
                                acc[isp][c4 * 4 + 2] = fmaf(x, wv.z, acc[isp][c4 * 4 + 2]);
                                acc[isp][c4 * 4 + 3] = fmaf(x, wv.w, acc[isp][c4 * 4 + 3]);
                            }
                        }
                    }
                }
            }
        }
        __syncthreads();
    }
#pragma unroll
    for (int isp = 0; isp < NSP; ++isp) {
        int sp = tid + isp * 256;
        if (sp < OSZ) {
            int oh = sp / OUT, ow = sp % OUT;
#pragma unroll
            for (int co = 0; co < CPB; ++co) {
                float y = acc[isp][co] + sB[co];
                out[(((size_t)b * COUT + co0 + co) * OUT + oh) * OUT + ow] =
                    (_Float16)fmaxf(y, 0.f);
            }
        }
    }
}

// ---------------------------------------------------------------------------
// conv2/conv3: implicit-GEMM MFMA (fp16 in, fp32 acc).
// grid (B, COUT/NPB, KSPL), block 256 (4 waves).
// A[m=sp][k=ci*KK+kh*Kk+kw] gathered into LDS fragment layout per K-chunk;
// B[n=co][k] read directly from flat f16 weights; fp32 atomic epilogue.
// ---------------------------------------------------------------------------
template<int CIN, int COUT, int Kk, int S, int IN, int OUT,
         int NPB, int KSPL, int KCH>
__global__ __launch_bounds__(256) void conv_mfma(
    const _Float16* __restrict__ in_h,   // [B][CIN][IN*IN]
    const _Float16* __restrict__ w_h,    // [COUT][CIN*KK]
    float* __restrict__ out)             // [B][COUT][OUT*OUT]
{
    constexpr int KK   = Kk * Kk;
    constexpr int OSZ  = OUT * OUT;
    constexpr int MT   = (OSZ + 15) / 16;   // m-tiles
    constexpr int MP   = MT * 16;
    constexpr int KTOT = CIN * KK;
    constexpr int KC   = KTOT / KSPL;       // k per block
    constexpr int NCHUNK = KC / KCH;
    constexpr int NT   = NPB / 64;          // n-tiles per wave
    constexpr int KSN  = KCH / 32;          // mfma k-steps per chunk
    constexpr int SLOTS = MP * (KCH / 8);

    const int b   = blockIdx.x;
    const int co0 = blockIdx.y * NPB;
    const int k00 = blockIdx.z * KC;
    const int tid  = threadIdx.x;
    const int wv   = tid >> 6;
    const int lane = tid & 63;
    const int quad = lane >> 4;
    const int mr   = lane & 15;

    __shared__ __align__(16) _Float16 A_lds[MP * KCH];

    const _Float16* inb = in_h + (size_t)b * CIN * (IN * IN);

    f32x4 acc[MT][NT];
#pragma unroll
    for (int mt = 0; mt < MT; ++mt)
#pragma unroll
        for (int nt = 0; nt < NT; ++nt) acc[mt][nt] = (f32x4){0.f, 0.f, 0.f, 0.f};

    for (int ch = 0; ch < NCHUNK; ++ch) {
        const int k0 = k00 + ch * KCH;
        __syncthreads();
        // ---- stage A chunk into fragment layout ----
        for (int slot = tid; slot < SLOTS; slot += 256) {
            int m  = slot % MP;
            int kg = slot / MP;
            bool mok = (m < OSZ);
            int oh = mok ? m / OUT : 0;
            int ow = mok ? m % OUT : 0;
            int kbase = k0 + kg * 8;
            f16x8 av;
#pragma unroll
            for (int j = 0; j < 8; ++j) {
                int k  = kbase + j;
                int ci = k / KK;
                int r  = k % KK;
                int kh = r / Kk, kw = r % Kk;
                _Float16 x = (_Float16)0.f;
                if (mok) x = inb[ci * (IN * IN) + (oh * S + kh) * IN + (ow * S + kw)];
                av[j] = x;
            }
            *(f16x8*)&A_lds[(kg * MP + m) * 8] = av;
        }
        __syncthreads();
        // ---- B fragments for this chunk (global, L2-resident) ----
        f16x8 bf[KSN][NT];
#pragma unroll
        for (int ks = 0; ks < KSN; ++ks)
#pragma unroll
            for (int nt = 0; nt < NT; ++nt) {
                int co = co0 + (wv * NT + nt) * 16 + mr;
                bf[ks][nt] = *(const f16x8*)&w_h[(size_t)co * KTOT + k0 + ks * 32 + quad * 8];
            }
        // ---- MFMA ----
#pragma unroll
        for (int ks = 0; ks < KSN; ++ks) {
#pragma unroll
            for (int mt = 0; mt < MT; ++mt) {
                f16x8 av = *(const f16x8*)&A_lds[((ks * 4 + quad) * MP + mt * 16 + mr) * 8];
#pragma unroll
                for (int nt = 0; nt < NT; ++nt)
                    acc[mt][nt] = __builtin_amdgcn_mfma_f32_16x16x32_f16(av, bf[ks][nt], acc[mt][nt], 0, 0, 0);
            }
        }
    }

    // epilogue: D[m = mt*16 + quad*4 + r][n = mr]
#pragma unroll
    for (int mt = 0; mt < MT; ++mt) {
#pragma unroll
        for (int nt = 0; nt < NT; ++nt) {
            int co = co0 + (wv * NT + nt) * 16 + mr;
#pragma unroll
            for (int r = 0; r < 4; ++r) {
                int sp = mt * 16 + quad * 4 + r;
                if (sp < OSZ)
                    atomicAdd(&out[((size_t)b * COUT + co) * OSZ + sp], acc[mt][nt][r]);
            }
        }
    }
}

// ---------------------------------------------------------------------------
// bias + ReLU (fp32 in-place).
// ---------------------------------------------------------------------------
__global__ __launch_bounds__(256) void bias_relu(
    float* __restrict__ x, const float* __restrict__ bias,
    int cout, int osz, int total)
{
    for (int i = blockIdx.x * 256 + threadIdx.x; i < total; i += gridDim.x * 256) {
        int co = (i / osz) % cout;
        x[i] = fmaxf(x[i] + bias[co], 0.f);
    }
}

// ---------------------------------------------------------------------------
// bias + ReLU, fp32 -> f16 output buffer.
// ---------------------------------------------------------------------------
__global__ __launch_bounds__(256) void bias_relu_f16(
    const float* __restrict__ x, const float* __restrict__ bias,
    _Float16* __restrict__ out, int cout, int osz, int total)
{
    for (int i = blockIdx.x * 256 + threadIdx.x; i < total; i += gridDim.x * 256) {
        int co = (i / osz) % cout;
        out[i] = (_Float16)fmaxf(x[i] + bias[co], 0.f);
    }
}

// ---------------------------------------------------------------------------
// fp32 -> f16 cast (weight prep).
// ---------------------------------------------------------------------------
__global__ __launch_bounds__(256) void cast_f16(
    const float* __restrict__ src, _Float16* __restrict__ dst, int n)
{
    for (int i = blockIdx.x * 256 + threadIdx.x; i < n; i += gridDim.x * 256)
        dst[i] = (_Float16)src[i];
}

// ---------------------------------------------------------------------------
// FC split-K: partial dot -> atomicAdd into out[b*NO+o] (pre-zeroed).
// ---------------------------------------------------------------------------
__global__ __launch_bounds__(256) void fc_atomic(
    const float* __restrict__ z, const float* __restrict__ fcw,
    float* __restrict__ out, int Kdim, int NO, int KSPL)
{
    const int b = blockIdx.x, o = blockIdx.y, ks = blockIdx.z;
    const int kchunk = Kdim / KSPL;
    const int k0 = ks * kchunk;
    const float* zp = z + (size_t)b * Kdim + k0;
    const float* wp = fcw + (size_t)o * Kdim + k0;
    float s = 0.f;
    for (int k = threadIdx.x; k < kchunk; k += 256) s = fmaf(zp[k], wp[k], s);
    __shared__ float red[4];
    for (int off = 32; off; off >>= 1) s += __shfl_down(s, off, 64);
    if ((threadIdx.x & 63) == 0) red[threadIdx.x >> 6] = s;
    __syncthreads();
    if (threadIdx.x == 0)
        atomicAdd(&out[(size_t)b * NO + o], red[0] + red[1] + red[2] + red[3]);
}

// ---------------------------------------------------------------------------
// m = reshape(|h|,3,3)^T; n = max L1 row norm + 1e-4; msc = m / n.
// ---------------------------------------------------------------------------
__global__ void build_m(const float* __restrict__ h, float* __restrict__ msc)
{
    int b = threadIdx.x;
    if (b < 16) {
        float m[9];
#pragma unroll
        for (int i = 0; i < 3; ++i)
#pragma unroll
            for (int j = 0; j < 3; ++j) m[i * 3 + j] = fabsf(h[b * 9 + j * 3 + i]);
        float n = 0.f;
#pragma unroll
        for (int i = 0; i < 3; ++i) {
            float r = m[i * 3] + m[i * 3 + 1] + m[i * 3 + 2];
            n = fmaxf(n, r);
        }
        n += 1e-4f;
        float inv = 1.f / n;
#pragma unroll
        for (int k = 0; k < 9; ++k) msc[b * 9 + k] = m[k] * inv;
    }
}

// ---------------------------------------------------------------------------
// est[b] = inv(msc[b]) @ |ill[b]|
// ---------------------------------------------------------------------------
__global__ void final_est(const float* __restrict__ msc, const float* __restrict__ ill,
                          float* __restrict__ out)
{
    int bidx = threadIdx.x;
    if (bidx < 16) {
        const float* m = msc + bidx * 9;
        float a = m[0], b = m[1], c = m[2];
        float d = m[3], e = m[4], f = m[5];
        float g = m[6], h = m[7], i = m[8];
        float A = e * i - f * h, B = f * g - d * i, C = d * h - e * g;
        float D = c * h - b * i, E = a * i - c * g, F = b * g - a * h;
        float G = b * f - c * e, H = c * d - a * f, I = a * e - b * d;
        float det = a * A + b * B + c * C;
        float inv_det = 1.f / det;
        float x0 = fabsf(ill[bidx * 3 + 0]);
        float x1 = fabsf(ill[bidx * 3 + 1]);
        float x2 = fabsf(ill[bidx * 3 + 2]);
        out[bidx * 3 + 0] = (A * x0 + D * x1 + G * x2) * inv_det;
        out[bidx * 3 + 1] = (B * x0 + E * x1 + H * x2) * inv_det;
        out[bidx * 3 + 2] = (C * x0 + F * x1 + I * x2) * inv_det;
    }
}

extern "C" void kernel_launch(void* const* d_in, const int* in_sizes, int n_in,
                              void* d_out, int out_size, void* d_ws, size_t ws_size,
                              hipStream_t stream)
{
    (void)in_sizes; (void)n_in; (void)out_size; (void)ws_size;
    const float* image = (const float*)d_in[0];
    const float* su_s  = (const float*)d_in[1];
    const float* sv_s  = (const float*)d_in[2];
    const float* c_s   = (const float*)d_in[3];
    const float* w1_s  = (const float*)d_in[4];
    const float* b1_s  = (const float*)d_in[5];
    const float* w2_s  = (const float*)d_in[6];
    const float* b2_s  = (const float*)d_in[7];
    const float* w3_s  = (const float*)d_in[8];
    const float* b3_s  = (const float*)d_in[9];
    const float* fc_s  = (const float*)d_in[10];
    const float* su_i  = (const float*)d_in[11];
    const float* sv_i  = (const float*)d_in[12];
    const float* c_i   = (const float*)d_in[13];
    const float* w1_i  = (const float*)d_in[14];
    const float* b1_i  = (const float*)d_in[15];
    const float* w2_i  = (const float*)d_in[16];
    const float* b2_i  = (const float*)d_in[17];
    const float* w3_i  = (const float*)d_in[18];
    const float* b3_i  = (const float*)d_in[19];
    const float* fc_i  = (const float*)d_in[20];

    // workspace layout (float units, 16B-aligned offsets)
    float* W     = (float*)d_ws;
    float* hist  = W;                       // 178608 f
    float* o2    = hist + 178608;           // 16*256*196 = 802816 f
    float* o3    = o2 + 802816;             // 16*512*169 = 1384448 f
    float* hd    = o3 + 1384448;            // 144
    float* msc   = hd + 144;                // 144 (total so far 2366160)
    _Float16* o1h   = (_Float16*)(msc + 144);          // 16*128*841 = 1722368 h -> 861184 f
    _Float16* o2h   = (_Float16*)(msc + 144 + 861184); // 802816 h -> 401408 f
    _Float16* w2h_s = (_Float16*)(msc + 144 + 861184 + 401408);            // 294912 h -> 147456 f
    _Float16* w3h_s = (_Float16*)(msc + 144 + 861184 + 401408 + 147456);   // 524288 h -> 262144 f
    _Float16* w2h_i = (_Float16*)(msc + 144 + 861184 + 401408 + 147456 + 262144);
    _Float16* w3h_i = (_Float16*)(msc + 144 + 861184 + 401408 + 147456 + 262144 + 147456);
    // total ~3.9M floats (~15.6 MB)

    const size_t HIST_BYTES = 178608u * sizeof(float);
    const int FCK = 512 * 13 * 13;
    const int O2_TOT = 16 * 256 * 196;
    const int O3_TOT = 16 * 512 * 169;

    // ---- weight prep (f16 flat casts) ----
    cast_f16<<<288, 256, 0, stream>>>(w2_s, w2h_s, 256 * 1152);
    cast_f16<<<512, 256, 0, stream>>>(w3_s, w3h_s, 512 * 1024);
    cast_f16<<<288, 256, 0, stream>>>(w2_i, w2h_i, 256 * 1152);
    cast_f16<<<512, 256, 0, stream>>>(w3_i, w3h_i, 512 * 1024);

    // ================= sensor branch =================
    hipMemsetAsync(hist, 0, HIST_BYTES, stream);
    hipMemsetAsync(o2, 0, (size_t)O2_TOT * 4, stream);
    hipMemsetAsync(o3, 0, (size_t)O3_TOT * 4, stream);
    hipMemsetAsync(hd, 0, 144 * 4, stream);
    hist_mfma<<<dim3(48, HSP), 256, 0, stream>>>(image, su_s, sv_s, c_s, nullptr, hist);
    norm_hist<<<16, 256, 0, stream>>>(hist);
    conv_relu<3, 128, 5, 2, 61, 29, 16, 3, 4><<<dim3(16, 8), 256, 0, stream>>>(hist, w1_s, b1_s, o1h);
    conv_mfma<128, 256, 3, 2, 29, 14, 128, 4, 96><<<dim3(16, 2, 4), 256, 0, stream>>>(o1h, w2h_s, o2);
    bias_relu_f16<<<1024, 256, 0, stream>>>(o2, b2_s, o2h, 256, 196, O2_TOT);
    conv_mfma<256, 512, 2, 1, 14, 13, 128, 4, 64><<<dim3(16, 4, 4), 256, 0, stream>>>(o2h, w3h_s, o3);
    bias_relu<<<1024, 256, 0, stream>>>(o3, b3_s, 512, 169, O3_TOT);
    fc_atomic<<<dim3(16, 9, 8), 256, 0, stream>>>(o3, fc_s, hd, FCK, 9, 8);
    build_m<<<1, 64, 0, stream>>>(hd, msc);

    // ================= illuminant branch =================
    hipMemsetAsync(hist, 0, HIST_BYTES, stream);
    hipMemsetAsync(o2, 0, (size_t)O2_TOT * 4, stream);
    hipMemsetAsync(o3, 0, (size_t)O3_TOT * 4, stream);
    hipMemsetAsync(hd, 0, 144 * 4, stream);
    hist_mfma<<<dim3(48, HSP), 256, 0, stream>>>(image, su_i, sv_i, c_i, msc, hist);
    norm_hist<<<16, 256, 0, stream>>>(hist);
    conv_relu<3, 128, 5, 2, 61, 29, 16, 3, 4><<<dim3(16, 8), 256, 0, stream>>>(hist, w1_i, b1_i, o1h);
    conv_mfma<128, 256, 3, 2, 29, 14, 128, 4, 96><<<dim3(16, 2, 4), 256, 0, stream>>>(o1h, w2h_i, o2);
    bias_relu_f16<<<1024, 256, 0, stream>>>(o2, b2_i, o2h, 256, 196, O2_TOT);
    conv_mfma<256, 512, 2, 1, 14, 13, 128, 4, 64><<<dim3(16, 4, 4), 256, 0, stream>>>(o2h, w3h_i, o3);
    bias_relu<<<1024, 256, 0, stream>>>(o3, b3_i, 512, 169, O3_TOT);
    fc_atomic<<<dim3(16, 3, 8), 256, 0, stream>>>(o3, fc_i, hd, FCK, 3, 8);
    final_est<<<1, 64, 0, stream>>>(msc, hd, (float*)d_out);
}

// Round 6
// 466.958 us; speedup vs baseline: 1.8501x; 1.8501x over previous
//
#include <hip/hip_runtime.h>

#define P_PIX 22500
#define HB 61
#define HSP 16           // pixel splits for hist
#define PPB 1408         // pixels per hist block (HSP*PPB >= P_PIX)
#define NCHK 11          // 128-px chunks per hist block

typedef float f32x4 __attribute__((ext_vector_type(4)));
typedef _Float16 f16x8 __attribute__((ext_vector_type(8)));

// ---------------------------------------------------------------------------
// MFMA RGB-uv soft histogram (fp16 fragments).  grid (48, HSP), block 256.
// hist[u,v] = sum_p (ku[p,u]*w[p]) * kv[p,v]  == GEMM M=N=64, K=P.
// ---------------------------------------------------------------------------
__global__ __launch_bounds__(256) void hist_mfma(
    const float* __restrict__ img, const float* __restrict__ su,
    const float* __restrict__ sv, const float* __restrict__ cw,
    const float* __restrict__ msc, float* __restrict__ hist)
{
    const int bc = blockIdx.x;
    const int b = bc / 3, c = bc % 3;
    const int split = blockIdx.y;
    const int tid  = threadIdx.x;
    const int w    = tid >> 6;      // wave id -> owns u-strip [16w,16w+16)
    const int lane = tid & 63;
    const int quad = lane >> 4;
    const int mr   = lane & 15;

    __shared__ __align__(16) _Float16 A_lds[8192];   // [pg(16)][u(64)][j(8)]
    __shared__ __align__(16) _Float16 B_lds[8192];
    __shared__ float suu[128], svv[128], sww[128];

    const float sig_u = su[c], sig_v = sv[c];
    const float inv_su2 = 1.f / (sig_u * sig_u);
    const float inv_sv2 = 1.f / (sig_v * sig_v);
    const float cwc = cw[c];

    const bool hasM = (msc != nullptr);
    float m00=0,m01=0,m02=0,m10=0,m11=0,m12=0,m20=0,m21=0,m22=0;
    if (hasM) {
        const float* mp = msc + b * 9;
        m00=mp[0]; m01=mp[1]; m02=mp[2];
        m10=mp[3]; m11=mp[4]; m12=mp[5];
        m20=mp[6]; m21=mp[7]; m22=mp[8];
    }

    const int p0   = split * PPB;
    const int pend = min(p0 + PPB, P_PIX);

    f32x4 acc[4];
#pragma unroll
    for (int nt = 0; nt < 4; ++nt) acc[nt] = (f32x4){0.f, 0.f, 0.f, 0.f};

    for (int chunk = 0; chunk < NCHK; ++chunk) {
        __syncthreads();
        if (tid < 128) {
            int px = p0 + chunk * 128 + tid;
            float u = 0.f, v = 0.f, wgt = 0.f;
            if (px < pend) {
                const float* ip = img + (size_t)b * 3 * P_PIX + px;
                float r = ip[0], g = ip[P_PIX], bl = ip[2 * P_PIX];
                if (hasM) {
                    float r2 = m00 * r + m01 * g + m02 * bl;
                    float g2 = m10 * r + m11 * g + m12 * bl;
                    float b2 = m20 * r + m21 * g + m22 * bl;
                    r = r2; g = g2; bl = b2;
                }
                r  = fminf(fmaxf(r, 0.f), 1.f);
                g  = fminf(fmaxf(g, 0.f), 1.f);
                bl = fminf(fmaxf(bl, 0.f), 1.f);
                float Iy = sqrtf(r * r + g * g + bl * bl);
                float lr = __logf(r + 1e-6f);
                float lg = __logf(g + 1e-6f);
                float lb = __logf(bl + 1e-6f);
                if (c == 0)      { u = lr - lg; v = lr - lb; }
                else if (c == 1) { u = lg - lr; v = lg - lb; }
                else             { u = lb - lr; v = lb - lg; }
                wgt = Iy * cwc;
            }
            suu[tid] = u; svv[tid] = v; sww[tid] = wgt;
        }
        __syncthreads();
#pragma unroll
        for (int r = 0; r < 4; ++r) {
            int idx = tid + 256 * r;
            int u  = idx & 63;
            int pg = idx >> 6;
            float ub = -3.f + 0.1f * (float)u;
            const float* up = &suu[pg * 8];
            const float* wp = &sww[pg * 8];
            f16x8 av;
#pragma unroll
            for (int j = 0; j < 8; ++j) {
                float du = up[j] - ub;
                av[j] = (_Float16)(__expf(-du * du * inv_su2) * wp[j]);
            }
            *(f16x8*)&A_lds[(pg * 64 + u) * 8] = av;
        }
#pragma unroll
        for (int r = 0; r < 4; ++r) {
            int idx = tid + 256 * r;
            int u  = idx & 63;
            int pg = idx >> 6;
            float ub = -3.f + 0.1f * (float)u;
            const float* vp = &svv[pg * 8];
            f16x8 bv;
#pragma unroll
            for (int j = 0; j < 8; ++j) {
                float dv = vp[j] - ub;
                bv[j] = (_Float16)__expf(-dv * dv * inv_sv2);
            }
            *(f16x8*)&B_lds[(pg * 64 + u) * 8] = bv;
        }
        __syncthreads();
#pragma unroll
        for (int kk = 0; kk < 4; ++kk) {
            int pgq = kk * 4 + quad;
            f16x8 av = *(const f16x8*)&A_lds[(pgq * 64 + w * 16 + mr) * 8];
#pragma unroll
            for (int nt = 0; nt < 4; ++nt) {
                f16x8 bv = *(const f16x8*)&B_lds[(pgq * 64 + nt * 16 + mr) * 8];
                acc[nt] = __builtin_amdgcn_mfma_f32_16x16x32_f16(av, bv, acc[nt], 0, 0, 0);
            }
        }
    }

    float* hp = hist + (size_t)bc * HB * HB;
#pragma unroll
    for (int nt = 0; nt < 4; ++nt) {
        int v = nt * 16 + mr;
        if (v >= HB) continue;
#pragma unroll
        for (int r = 0; r < 4; ++r) {
            int u = w * 16 + quad * 4 + r;
            if (u < HB) atomicAdd(&hp[u * HB + v], acc[nt][r]);
        }
    }
}

// ---------------------------------------------------------------------------
// Per-batch normalization: hist /= (sum + 1e-6).  grid 16, block 256.
// ---------------------------------------------------------------------------
__global__ __launch_bounds__(256) void norm_hist(float* __restrict__ hist)
{
    const int b = blockIdx.x;
    float* hp = hist + (size_t)b * 3 * HB * HB;
    const int N = 3 * HB * HB;
    float s = 0.f;
    for (int i = threadIdx.x; i < N; i += 256) s += hp[i];
    __shared__ float red[4];
    for (int off = 32; off; off >>= 1) s += __shfl_down(s, off, 64);
    if ((threadIdx.x & 63) == 0) red[threadIdx.x >> 6] = s;
    __syncthreads();
    float inv = 1.f / (red[0] + red[1] + red[2] + red[3] + 1e-6f);
    for (int i = threadIdx.x; i < N; i += 256) hp[i] *= inv;
}

// ---------------------------------------------------------------------------
// conv1: direct fp32 conv + bias + ReLU, writes f16 output.
// ---------------------------------------------------------------------------
template<int CIN, int COUT, int K, int S, int IN, int OUT, int CPB, int CCH, int NSP>
__global__ __launch_bounds__(256) void conv_relu(
    const float* __restrict__ in, const float* __restrict__ wt,
    const float* __restrict__ bias, _Float16* __restrict__ out)
{
    constexpr int NCH = CIN / CCH;
    constexpr int OSZ = OUT * OUT;
    const int b = blockIdx.x;
    const int co0 = blockIdx.y * CPB;
    const int tid = threadIdx.x;

    __shared__ __align__(16) float sIn[CCH * IN * IN];
    __shared__ __align__(16) float sW[CCH * K * K * CPB];
    __shared__ float sB[CPB];
    if (tid < CPB) sB[tid] = bias[co0 + tid];

    float acc[NSP][CPB];
#pragma unroll
    for (int i = 0; i < NSP; ++i)
#pragma unroll
        for (int j = 0; j < CPB; ++j) acc[i][j] = 0.f;

    for (int ch = 0; ch < NCH; ++ch) {
        const float* gin = in + ((size_t)b * CIN + ch * CCH) * (IN * IN);
        for (int i = tid; i < CCH * IN * IN; i += 256) sIn[i] = gin[i];
        const float* gwt = wt + (size_t)co0 * CIN * K * K + (size_t)ch * CCH * K * K;
        for (int i = tid; i < CCH * K * K * CPB; i += 256) {
            int co = i % CPB;
            int r  = i / CPB;
            sW[i] = gwt[(size_t)co * CIN * K * K + r];
        }
        __syncthreads();
#pragma unroll
        for (int isp = 0; isp < NSP; ++isp) {
            int sp = tid + isp * 256;
            if (sp < OSZ) {
                int oh = sp / OUT, ow = sp % OUT;
                const float* ibase = &sIn[(oh * S) * IN + ow * S];
                for (int ci = 0; ci < CCH; ++ci) {
#pragma unroll
                    for (int kh = 0; kh < K; ++kh) {
#pragma unroll
                        for (int kw = 0; kw < K; ++kw) {
                            float x = ibase[ci * IN * IN + kh * IN + kw];
                            const float4* w4 =
                                (const float4*)&sW[(ci * K * K + kh * K + kw) * CPB];
#pragma unroll
                            for (int c4 = 0; c4 < CPB / 4; ++c4) {
                                float4 wv = w4[c4];
                                acc[isp][c4 * 4 + 0] = fmaf(x, wv.x, acc[isp][c4 * 4 + 0]);
                                acc[isp][c4 * 4 + 1] = fmaf(x, wv.y, acc[isp][c4 * 4 + 1]);
                                acc[isp][c4 * 4 + 2] = fmaf(x, wv.z, acc[isp][c4 * 4 + 2]);
                                acc[isp][c4 * 4 + 3] = fmaf(x, wv.w, acc[isp][c4 * 4 + 3]);
                            }
                        }
                    }
                }
            }
        }
        __syncthreads();
    }
#pragma unroll
    for (int isp = 0; isp < NSP; ++isp) {
        int sp = tid + isp * 256;
        if (sp < OSZ) {
            int oh = sp / OUT, ow = sp % OUT;
#pragma unroll
            for (int co = 0; co < CPB; ++co) {
                float y = acc[isp][co] + sB[co];
                out[(((size_t)b * COUT + co0 + co) * OUT + oh) * OUT + ow] =
                    (_Float16)fmaxf(y, 0.f);
            }
        }
    }
}

// ---------------------------------------------------------------------------
// conv2/conv3: implicit-GEMM MFMA (fp16 in, fp32 acc).
// grid (B, COUT/NPB, KSPL), block 256 (4 waves).
// WEIGHTS are the A operand (rows=co), ACTIVATIONS the B operand (cols=sp)
// so D cols = consecutive sp -> coalesced stores.  Split-K partials go to
// private slabs (no atomics); reduce+bias+relu fused in a follow-up pass.
// ---------------------------------------------------------------------------
template<int CIN, int COUT, int Kk, int S, int IN, int OUT,
         int NPB, int KSPL, int KCH>
__global__ __launch_bounds__(256) void conv_mfma(
    const _Float16* __restrict__ in_h,   // [B][CIN][IN*IN]
    const _Float16* __restrict__ w_h,    // [COUT][CIN*KK]
    float* __restrict__ out)             // [KSPL][B][COUT][OUT*OUT]
{
    constexpr int KK   = Kk * Kk;
    constexpr int OSZ  = OUT * OUT;
    constexpr int MT   = (OSZ + 15) / 16;   // sp-tiles
    constexpr int MP   = MT * 16;
    constexpr int KTOT = CIN * KK;
    constexpr int KC   = KTOT / KSPL;       // k per block
    constexpr int NCHUNK = KC / KCH;
    constexpr int NT   = NPB / 64;          // co-tiles per wave
    constexpr int KSN  = KCH / 32;          // mfma k-steps per chunk
    constexpr int SLOTS = MP * (KCH / 8);

    const int b   = blockIdx.x;
    const int co0 = blockIdx.y * NPB;
    const int k00 = blockIdx.z * KC;
    const int tid  = threadIdx.x;
    const int wv   = tid >> 6;
    const int lane = tid & 63;
    const int quad = lane >> 4;
    const int mr   = lane & 15;

    __shared__ __align__(16) _Float16 A_lds[MP * KCH];

    const _Float16* inb = in_h + (size_t)b * CIN * (IN * IN);
    float* outp = out + (size_t)blockIdx.z * gridDim.x * COUT * OSZ;

    f32x4 acc[MT][NT];
#pragma unroll
    for (int mt = 0; mt < MT; ++mt)
#pragma unroll
        for (int nt = 0; nt < NT; ++nt) acc[mt][nt] = (f32x4){0.f, 0.f, 0.f, 0.f};

    for (int ch = 0; ch < NCHUNK; ++ch) {
        const int k0 = k00 + ch * KCH;
        __syncthreads();
        // ---- stage activation chunk into fragment layout ----
        for (int slot = tid; slot < SLOTS; slot += 256) {
            int m  = slot % MP;
            int kg = slot / MP;
            bool mok = (m < OSZ);
            int oh = mok ? m / OUT : 0;
            int ow = mok ? m % OUT : 0;
            int kbase = k0 + kg * 8;
            f16x8 av;
#pragma unroll
            for (int j = 0; j < 8; ++j) {
                int k  = kbase + j;
                int ci = k / KK;
                int r  = k % KK;
                int kh = r / Kk, kw = r % Kk;
                _Float16 x = (_Float16)0.f;
                if (mok) x = inb[ci * (IN * IN) + (oh * S + kh) * IN + (ow * S + kw)];
                av[j] = x;
            }
            *(f16x8*)&A_lds[(kg * MP + m) * 8] = av;
        }
        __syncthreads();
        // ---- weight fragments (A operand) for this chunk ----
        f16x8 wf[KSN][NT];
#pragma unroll
        for (int ks = 0; ks < KSN; ++ks)
#pragma unroll
            for (int nt = 0; nt < NT; ++nt) {
                int co = co0 + (wv * NT + nt) * 16 + mr;
                wf[ks][nt] = *(const f16x8*)&w_h[(size_t)co * KTOT + k0 + ks * 32 + quad * 8];
            }
        // ---- MFMA: A=weights, B=activations ----
#pragma unroll
        for (int ks = 0; ks < KSN; ++ks) {
#pragma unroll
            for (int mt = 0; mt < MT; ++mt) {
                f16x8 bv = *(const f16x8*)&A_lds[((ks * 4 + quad) * MP + mt * 16 + mr) * 8];
#pragma unroll
                for (int nt = 0; nt < NT; ++nt)
                    acc[mt][nt] = __builtin_amdgcn_mfma_f32_16x16x32_f16(wf[ks][nt], bv, acc[mt][nt], 0, 0, 0);
            }
        }
    }

    // epilogue: D[row=co-within-tile=quad*4+r][col=sp-within-tile=mr]
#pragma unroll
    for (int mt = 0; mt < MT; ++mt) {
        int sp = mt * 16 + mr;
        if (sp >= OSZ) continue;
#pragma unroll
        for (int nt = 0; nt < NT; ++nt) {
#pragma unroll
            for (int r = 0; r < 4; ++r) {
                int co = co0 + (wv * NT + nt) * 16 + quad * 4 + r;
                outp[((size_t)b * COUT + co) * OSZ + sp] = acc[mt][nt][r];
            }
        }
    }
}

// ---------------------------------------------------------------------------
// sum KSPL split-K partials + bias + ReLU -> f16 out.
// ---------------------------------------------------------------------------
__global__ __launch_bounds__(256) void reduce_bias_relu_f16(
    const float* __restrict__ p, const float* __restrict__ bias,
    _Float16* __restrict__ out, int cout, int osz, int total, int kspl)
{
    for (int i = blockIdx.x * 256 + threadIdx.x; i < total; i += gridDim.x * 256) {
        float s = 0.f;
        for (int ks = 0; ks < kspl; ++ks) s += p[(size_t)ks * total + i];
        int co = (i / osz) % cout;
        out[i] = (_Float16)fmaxf(s + bias[co], 0.f);
    }
}

// ---------------------------------------------------------------------------
// sum KSPL split-K partials + bias + ReLU -> fp32 out.
// ---------------------------------------------------------------------------
__global__ __launch_bounds__(256) void reduce_bias_relu(
    const float* __restrict__ p, const float* __restrict__ bias,
    float* __restrict__ out, int cout, int osz, int total, int kspl)
{
    for (int i = blockIdx.x * 256 + threadIdx.x; i < total; i += gridDim.x * 256) {
        float s = 0.f;
        for (int ks = 0; ks < kspl; ++ks) s += p[(size_t)ks * total + i];
        int co = (i / osz) % cout;
        out[i] = fmaxf(s + bias[co], 0.f);
    }
}

// ---------------------------------------------------------------------------
// fp32 -> f16 cast (weight prep).
// ---------------------------------------------------------------------------
__global__ __launch_bounds__(256) void cast_f16(
    const float* __restrict__ src, _Float16* __restrict__ dst, int n)
{
    for (int i = blockIdx.x * 256 + threadIdx.x; i < n; i += gridDim.x * 256)
        dst[i] = (_Float16)src[i];
}

// ---------------------------------------------------------------------------
// FC split-K: partial dot -> atomicAdd into out[b*NO+o] (pre-zeroed).
// ---------------------------------------------------------------------------
__global__ __launch_bounds__(256) void fc_atomic(
    const float* __restrict__ z, const float* __restrict__ fcw,
    float* __restrict__ out, int Kdim, int NO, int KSPL)
{
    const int b = blockIdx.x, o = blockIdx.y, ks = blockIdx.z;
    const int kchunk = Kdim / KSPL;
    const int k0 = ks * kchunk;
    const float* zp = z + (size_t)b * Kdim + k0;
    const float* wp = fcw + (size_t)o * Kdim + k0;
    float s = 0.f;
    for (int k = threadIdx.x; k < kchunk; k += 256) s = fmaf(zp[k], wp[k], s);
    __shared__ float red[4];
    for (int off = 32; off; off >>= 1) s += __shfl_down(s, off, 64);
    if ((threadIdx.x & 63) == 0) red[threadIdx.x >> 6] = s;
    __syncthreads();
    if (threadIdx.x == 0)
        atomicAdd(&out[(size_t)b * NO + o], red[0] + red[1] + red[2] + red[3]);
}

// ---------------------------------------------------------------------------
// m = reshape(|h|,3,3)^T; n = max L1 row norm + 1e-4; msc = m / n.
// ---------------------------------------------------------------------------
__global__ void build_m(const float* __restrict__ h, float* __restrict__ msc)
{
    int b = threadIdx.x;
    if (b < 16) {
        float m[9];
#pragma unroll
        for (int i = 0; i < 3; ++i)
#pragma unroll
            for (int j = 0; j < 3; ++j) m[i * 3 + j] = fabsf(h[b * 9 + j * 3 + i]);
        float n = 0.f;
#pragma unroll
        for (int i = 0; i < 3; ++i) {
            float r = m[i * 3] + m[i * 3 + 1] + m[i * 3 + 2];
            n = fmaxf(n, r);
        }
        n += 1e-4f;
        float inv = 1.f / n;
#pragma unroll
        for (int k = 0; k < 9; ++k) msc[b * 9 + k] = m[k] * inv;
    }
}

// ---------------------------------------------------------------------------
// est[b] = inv(msc[b]) @ |ill[b]|
// ---------------------------------------------------------------------------
__global__ void final_est(const float* __restrict__ msc, const float* __restrict__ ill,
                          float* __restrict__ out)
{
    int bidx = threadIdx.x;
    if (bidx < 16) {
        const float* m = msc + bidx * 9;
        float a = m[0], b = m[1], c = m[2];
        float d = m[3], e = m[4], f = m[5];
        float g = m[6], h = m[7], i = m[8];
        float A = e * i - f * h, B = f * g - d * i, C = d * h - e * g;
        float D = c * h - b * i, E = a * i - c * g, F = b * g - a * h;
        float G = b * f - c * e, H = c * d - a * f, I = a * e - b * d;
        float det = a * A + b * B + c * C;
        float inv_det = 1.f / det;
        float x0 = fabsf(ill[bidx * 3 + 0]);
        float x1 = fabsf(ill[bidx * 3 + 1]);
        float x2 = fabsf(ill[bidx * 3 + 2]);
        out[bidx * 3 + 0] = (A * x0 + D * x1 + G * x2) * inv_det;
        out[bidx * 3 + 1] = (B * x0 + E * x1 + H * x2) * inv_det;
        out[bidx * 3 + 2] = (C * x0 + F * x1 + I * x2) * inv_det;
    }
}

extern "C" void kernel_launch(void* const* d_in, const int* in_sizes, int n_in,
                              void* d_out, int out_size, void* d_ws, size_t ws_size,
                              hipStream_t stream)
{
    (void)in_sizes; (void)n_in; (void)out_size; (void)ws_size;
    const float* image = (const float*)d_in[0];
    const float* su_s  = (const float*)d_in[1];
    const float* sv_s  = (const float*)d_in[2];
    const float* c_s   = (const float*)d_in[3];
    const float* w1_s  = (const float*)d_in[4];
    const float* b1_s  = (const float*)d_in[5];
    const float* w2_s  = (const float*)d_in[6];
    const float* b2_s  = (const float*)d_in[7];
    const float* w3_s  = (const float*)d_in[8];
    const float* b3_s  = (const float*)d_in[9];
    const float* fc_s  = (const float*)d_in[10];
    const float* su_i  = (const float*)d_in[11];
    const float* sv_i  = (const float*)d_in[12];
    const float* c_i   = (const float*)d_in[13];
    const float* w1_i  = (const float*)d_in[14];
    const float* b1_i  = (const float*)d_in[15];
    const float* w2_i  = (const float*)d_in[16];
    const float* b2_i  = (const float*)d_in[17];
    const float* w3_i  = (const float*)d_in[18];
    const float* b3_i  = (const float*)d_in[19];
    const float* fc_i  = (const float*)d_in[20];

    // workspace layout (float units)
    float* W     = (float*)d_ws;
    float* hist  = W;                         // 178608 f
    float* o3    = hist + 178608;             // 1384448 f
    float* hd    = o3 + 1384448;              // 144
    float* msc   = hd + 144;                  // 144
    float* p2    = msc + 144;                 // 4*802816  = 3211264 f
    float* p3    = p2 + 3211264;              // 4*1384448 = 5537792 f
    _Float16* o1h   = (_Float16*)(p3 + 5537792);          // 1722368 h -> 861184 f
    _Float16* o2h   = (_Float16*)(p3 + 5537792 + 861184); // 802816 h -> 401408 f
    _Float16* w2h_s = (_Float16*)(p3 + 5537792 + 861184 + 401408);
    _Float16* w3h_s = (_Float16*)(p3 + 5537792 + 861184 + 401408 + 147456);
    _Float16* w2h_i = (_Float16*)(p3 + 5537792 + 861184 + 401408 + 147456 + 262144);
    _Float16* w3h_i = (_Float16*)(p3 + 5537792 + 861184 + 401408 + 147456 + 262144 + 147456);
    // total ~12.4M floats (~50 MB)

    const size_t HIST_BYTES = 178608u * sizeof(float);
    const int FCK = 512 * 13 * 13;
    const int O2_TOT = 16 * 256 * 196;
    const int O3_TOT = 16 * 512 * 169;

    // ---- weight prep (f16 flat casts) ----
    cast_f16<<<288, 256, 0, stream>>>(w2_s, w2h_s, 256 * 1152);
    cast_f16<<<512, 256, 0, stream>>>(w3_s, w3h_s, 512 * 1024);
    cast_f16<<<288, 256, 0, stream>>>(w2_i, w2h_i, 256 * 1152);
    cast_f16<<<512, 256, 0, stream>>>(w3_i, w3h_i, 512 * 1024);

    // ================= sensor branch =================
    hipMemsetAsync(hist, 0, HIST_BYTES, stream);
    hipMemsetAsync(hd, 0, 144 * 4, stream);
    hist_mfma<<<dim3(48, HSP), 256, 0, stream>>>(image, su_s, sv_s, c_s, nullptr, hist);
    norm_hist<<<16, 256, 0, stream>>>(hist);
    conv_relu<3, 128, 5, 2, 61, 29, 16, 3, 4><<<dim3(16, 8), 256, 0, stream>>>(hist, w1_s, b1_s, o1h);
    conv_mfma<128, 256, 3, 2, 29, 14, 128, 4, 96><<<dim3(16, 2, 4), 256, 0, stream>>>(o1h, w2h_s, p2);
    reduce_bias_relu_f16<<<1024, 256, 0, stream>>>(p2, b2_s, o2h, 256, 196, O2_TOT, 4);
    conv_mfma<256, 512, 2, 1, 14, 13, 128, 4, 64><<<dim3(16, 4, 4), 256, 0, stream>>>(o2h, w3h_s, p3);
    reduce_bias_relu<<<1024, 256, 0, stream>>>(p3, b3_s, o3, 512, 169, O3_TOT, 4);
    fc_atomic<<<dim3(16, 9, 8), 256, 0, stream>>>(o3, fc_s, hd, FCK, 9, 8);
    build_m<<<1, 64, 0, stream>>>(hd, msc);

    // ================= illuminant branch =================
    hipMemsetAsync(hist, 0, HIST_BYTES, stream);
    hipMemsetAsync(hd, 0, 144 * 4, stream);
    hist_mfma<<<dim3(48, HSP), 256, 0, stream>>>(image, su_i, sv_i, c_i, msc, hist);
    norm_hist<<<16, 256, 0, stream>>>(hist);
    conv_relu<3, 128, 5, 2, 61, 29, 16, 3, 4><<<dim3(16, 8), 256, 0, stream>>>(hist, w1_i, b1_i, o1h);
    conv_mfma<128, 256, 3, 2, 29, 14, 128, 4, 96><<<dim3(16, 2, 4), 256, 0, stream>>>(o1h, w2h_i, p2);
    reduce_bias_relu_f16<<<1024, 256, 0, stream>>>(p2, b2_i, o2h, 256, 196, O2_TOT, 4);
    conv_mfma<256, 512, 2, 1, 14, 13, 128, 4, 64><<<dim3(16, 4, 4), 256, 0, stream>>>(o2h, w3h_i, p3);
    reduce_bias_relu<<<1024, 256, 0, stream>>>(p3, b3_i, o3, 512, 169, O3_TOT, 4);
    fc_atomic<<<dim3(16, 3, 8), 256, 0, stream>>>(o3, fc_i, hd, FCK, 3, 8);
    final_est<<<1, 64, 0, stream>>>(msc, hd, (float*)d_out);
}

// Round 9
// 450.571 us; speedup vs baseline: 1.9174x; 1.0364x over previous
//
#include <hip/hip_runtime.h>

#define P_PIX 22500
#define HB 61
#define HSP 16           // pixel splits for hist
#define PPB 1408         // pixels per hist block (HSP*PPB >= P_PIX)
#define NCHK 11          // 128-px chunks per hist block

typedef float f32x4 __attribute__((ext_vector_type(4)));
typedef _Float16 f16x8 __attribute__((ext_vector_type(8)));

// ---------------------------------------------------------------------------
// MFMA RGB-uv soft histogram (fp16 fragments).  grid (48, HSP), block 256.
// hist[u,v] = sum_p (ku[p,u]*w[p]) * kv[p,v]  == GEMM M=N=64, K=P.
// Phase-2: factored Gaussian arg (du=u-b; -du*du*inv) -- do NOT expand the
// quadratic (fp32 cancellation, r7 post-mortem); wave-uniform f32x4 preloads.
// ---------------------------------------------------------------------------
__global__ __launch_bounds__(256) void hist_mfma(
    const float* __restrict__ img, const float* __restrict__ su,
    const float* __restrict__ sv, const float* __restrict__ cw,
    const float* __restrict__ msc, float* __restrict__ hist)
{
    const int bc = blockIdx.x;
    const int b = bc / 3, c = bc % 3;
    const int split = blockIdx.y;
    const int tid  = threadIdx.x;
    const int wv   = tid >> 6;      // wave id -> owns u-strip [16wv,16wv+16)
    const int lane = tid & 63;
    const int quad = lane >> 4;
    const int mr   = lane & 15;

    __shared__ __align__(16) _Float16 A_lds[8192];   // [pg(16)][u(64)][j(8)]
    __shared__ __align__(16) _Float16 B_lds[8192];
    __shared__ float suu[128], svv[128], sww[128];

    const float sig_u = su[c], sig_v = sv[c];
    const float inv_su2 = 1.f / (sig_u * sig_u);
    const float inv_sv2 = 1.f / (sig_v * sig_v);
    const float cwc = cw[c];

    // per-thread bin value: lane == bin index for phase-2 writes
    const float ubin = -3.f + 0.1f * (float)lane;

    const bool hasM = (msc != nullptr);
    float m00=0,m01=0,m02=0,m10=0,m11=0,m12=0,m20=0,m21=0,m22=0;
    if (hasM) {
        const float* mp = msc + b * 9;
        m00=mp[0]; m01=mp[1]; m02=mp[2];
        m10=mp[3]; m11=mp[4]; m12=mp[5];
        m20=mp[6]; m21=mp[7]; m22=mp[8];
    }

    const int p0   = split * PPB;
    const int pend = min(p0 + PPB, P_PIX);

    f32x4 acc[4];
#pragma unroll
    for (int nt = 0; nt < 4; ++nt) acc[nt] = (f32x4){0.f, 0.f, 0.f, 0.f};

    for (int chunk = 0; chunk < NCHK; ++chunk) {
        __syncthreads();
        // ---- phase 1: (u, v, weight) for 128 pixels ----
        if (tid < 128) {
            int px = p0 + chunk * 128 + tid;
            float u = 0.f, v = 0.f, wgt = 0.f;
            if (px < pend) {
                const float* ip = img + (size_t)b * 3 * P_PIX + px;
                float r = ip[0], g = ip[P_PIX], bl = ip[2 * P_PIX];
                if (hasM) {
                    float r2 = m00 * r + m01 * g + m02 * bl;
                    float g2 = m10 * r + m11 * g + m12 * bl;
                    float b2 = m20 * r + m21 * g + m22 * bl;
                    r = r2; g = g2; bl = b2;
                }
                r  = fminf(fmaxf(r, 0.f), 1.f);
                g  = fminf(fmaxf(g, 0.f), 1.f);
                bl = fminf(fmaxf(bl, 0.f), 1.f);
                float Iy = sqrtf(r * r + g * g + bl * bl);
                float lr = __logf(r + 1e-6f);
                float lg = __logf(g + 1e-6f);
                float lb = __logf(bl + 1e-6f);
                if (c == 0)      { u = lr - lg; v = lr - lb; }
                else if (c == 1) { u = lg - lr; v = lg - lb; }
                else             { u = lb - lr; v = lb - lg; }
                wgt = Iy * cwc;
            }
            suu[tid] = u; svv[tid] = v; sww[tid] = wgt;
        }
        __syncthreads();
        // ---- phase 2: f16 fragment tables (A = ku*w, B = kv) ----
#pragma unroll
        for (int r = 0; r < 4; ++r) {
            int pg = wv + 4 * r;           // wave-uniform pixel group
            f32x4 u0 = *(const f32x4*)&suu[pg * 8];
            f32x4 u1 = *(const f32x4*)&suu[pg * 8 + 4];
            f32x4 w0 = *(const f32x4*)&sww[pg * 8];
            f32x4 w1 = *(const f32x4*)&sww[pg * 8 + 4];
            f32x4 v0 = *(const f32x4*)&svv[pg * 8];
            f32x4 v1 = *(const f32x4*)&svv[pg * 8 + 4];
            f16x8 av, bv;
#pragma unroll
            for (int j = 0; j < 4; ++j) {
                float du = u0[j] - ubin;
                av[j] = (_Float16)(__expf(-du * du * inv_su2) * w0[j]);
                float dv = v0[j] - ubin;
                bv[j] = (_Float16)__expf(-dv * dv * inv_sv2);
            }
#pragma unroll
            for (int j = 0; j < 4; ++j) {
                float du = u1[j] - ubin;
                av[4 + j] = (_Float16)(__expf(-du * du * inv_su2) * w1[j]);
                float dv = v1[j] - ubin;
                bv[4 + j] = (_Float16)__expf(-dv * dv * inv_sv2);
            }
            *(f16x8*)&A_lds[(pg * 64 + lane) * 8] = av;
            *(f16x8*)&B_lds[(pg * 64 + lane) * 8] = bv;
        }
        __syncthreads();
        // ---- phase 3: MFMA ----
#pragma unroll
        for (int kk = 0; kk < 4; ++kk) {
            int pgq = kk * 4 + quad;
            f16x8 av = *(const f16x8*)&A_lds[(pgq * 64 + wv * 16 + mr) * 8];
#pragma unroll
            for (int nt = 0; nt < 4; ++nt) {
                f16x8 bvv = *(const f16x8*)&B_lds[(pgq * 64 + nt * 16 + mr) * 8];
                acc[nt] = __builtin_amdgcn_mfma_f32_16x16x32_f16(av, bvv, acc[nt], 0, 0, 0);
            }
        }
    }

    float* hp = hist + (size_t)bc * HB * HB;
#pragma unroll
    for (int nt = 0; nt < 4; ++nt) {
        int v = nt * 16 + mr;
        if (v >= HB) continue;
#pragma unroll
        for (int r = 0; r < 4; ++r) {
            int u = wv * 16 + quad * 4 + r;
            if (u < HB) atomicAdd(&hp[u * HB + v], acc[nt][r]);
        }
    }
}

// ---------------------------------------------------------------------------
// Per-batch normalization: hist /= (sum + 1e-6).  grid 16, block 256.
// ---------------------------------------------------------------------------
__global__ __launch_bounds__(256) void norm_hist(float* __restrict__ hist)
{
    const int b = blockIdx.x;
    float* hp = hist + (size_t)b * 3 * HB * HB;
    const int N = 3 * HB * HB;
    float s = 0.f;
    for (int i = threadIdx.x; i < N; i += 256) s += hp[i];
    __shared__ float red[4];
    for (int off = 32; off; off >>= 1) s += __shfl_down(s, off, 64);
    if ((threadIdx.x & 63) == 0) red[threadIdx.x >> 6] = s;
    __syncthreads();
    float inv = 1.f / (red[0] + red[1] + red[2] + red[3] + 1e-6f);
    for (int i = threadIdx.x; i < N; i += 256) hp[i] *= inv;
}

// ---------------------------------------------------------------------------
// conv1 as implicit-GEMM MFMA: M=841 sp, N=128 co, K=75 (pad 96).
// grid (16, 7), block 256.  A=weights (global f16), B=activations (LDS,
// gathered from fp32 hist).  Bias+ReLU fused; writes f16 o1 directly.
// ---------------------------------------------------------------------------
__global__ __launch_bounds__(256) void conv1_mfma(
    const float* __restrict__ hist,     // [B][3][3721]
    const _Float16* __restrict__ w1h,   // [128][96] (zero-padded)
    const float* __restrict__ bias,     // [128]
    _Float16* __restrict__ out)         // [B][128][841]
{
    const int b    = blockIdx.x;
    const int m0   = blockIdx.y * 128;
    const int tid  = threadIdx.x;
    const int wv   = tid >> 6;
    const int lane = tid & 63;
    const int quad = lane >> 4;
    const int mr   = lane & 15;

    __shared__ __align__(16) _Float16 A_lds[128 * 96];   // [kg(12)][m(128)][8]

    const float* inb = hist + (size_t)b * 3 * 3721;

    // stage activations into fragment layout
    for (int slot = tid; slot < 1536; slot += 256) {
        int m  = slot & 127;
        int kg = slot >> 7;
        int mg = m0 + m;
        bool mok = (mg < 841);
        int oh = mok ? mg / 29 : 0;
        int ow = mok ? mg % 29 : 0;
        const float* pbase = inb + (oh * 2) * 61 + (ow * 2);
        f16x8 av;
#pragma unroll
        for (int j = 0; j < 8; ++j) {
            int k = kg * 8 + j;
            float x = 0.f;
            if (mok && k < 75) {
                int ci = k / 25, r = k % 25;
                int kh = r / 5, kw = r % 5;
                x = pbase[ci * 3721 + kh * 61 + kw];
            }
            av[j] = (_Float16)x;
        }
        *(f16x8*)&A_lds[(kg * 128 + m) * 8] = av;
    }
    __syncthreads();

    // weight fragments (A operand)
    f16x8 wf[3][2];
#pragma unroll
    for (int ks = 0; ks < 3; ++ks)
#pragma unroll
        for (int nt = 0; nt < 2; ++nt) {
            int co = (wv * 2 + nt) * 16 + mr;
            wf[ks][nt] = *(const f16x8*)&w1h[co * 96 + ks * 32 + quad * 8];
        }

    f32x4 acc[8][2];
#pragma unroll
    for (int mt = 0; mt < 8; ++mt)
#pragma unroll
        for (int nt = 0; nt < 2; ++nt) acc[mt][nt] = (f32x4){0.f, 0.f, 0.f, 0.f};

#pragma unroll
    for (int ks = 0; ks < 3; ++ks)
#pragma unroll
        for (int mt = 0; mt < 8; ++mt) {
            f16x8 bv = *(const f16x8*)&A_lds[((ks * 4 + quad) * 128 + mt * 16 + mr) * 8];
#pragma unroll
            for (int nt = 0; nt < 2; ++nt)
                acc[mt][nt] = __builtin_amdgcn_mfma_f32_16x16x32_f16(wf[ks][nt], bv, acc[mt][nt], 0, 0, 0);
        }

    // epilogue: D[row=co local][col=sp local]; bias + relu, f16 store
#pragma unroll
    for (int mt = 0; mt < 8; ++mt) {
        int sp = m0 + mt * 16 + mr;
        if (sp >= 841) continue;
#pragma unroll
        for (int nt = 0; nt < 2; ++nt) {
#pragma unroll
            for (int r = 0; r < 4; ++r) {
                int co = (wv * 2 + nt) * 16 + quad * 4 + r;
                float y = acc[mt][nt][r] + bias[co];
                out[((size_t)b * 128 + co) * 841 + sp] = (_Float16)fmaxf(y, 0.f);
            }
        }
    }
}

// ---------------------------------------------------------------------------
// conv2/conv3: implicit-GEMM MFMA (fp16 in, fp32 acc).
// grid (B, COUT/NPB, KSPL), block 256 (4 waves).  A=weights, B=activations;
// split-K partials to private slabs; reduce+bias+relu afterwards.
// ---------------------------------------------------------------------------
template<int CIN, int COUT, int Kk, int S, int IN, int OUT,
         int NPB, int KSPL, int KCH>
__global__ __launch_bounds__(256) void conv_mfma(
    const _Float16* __restrict__ in_h,   // [B][CIN][IN*IN]
    const _Float16* __restrict__ w_h,    // [COUT][CIN*KK]
    float* __restrict__ out)             // [KSPL][B][COUT][OUT*OUT]
{
    constexpr int KK   = Kk * Kk;
    constexpr int OSZ  = OUT * OUT;
    constexpr int MT   = (OSZ + 15) / 16;   // sp-tiles
    constexpr int MP   = MT * 16;
    constexpr int KTOT = CIN * KK;
    constexpr int KC   = KTOT / KSPL;       // k per block
    constexpr int NCHUNK = KC / KCH;
    constexpr int NT   = NPB / 64;          // co-tiles per wave
    constexpr int KSN  = KCH / 32;          // mfma k-steps per chunk
    constexpr int SLOTS = MP * (KCH / 8);

    const int b   = blockIdx.x;
    const int co0 = blockIdx.y * NPB;
    const int k00 = blockIdx.z * KC;
    const int tid  = threadIdx.x;
    const int wv   = tid >> 6;
    const int lane = tid & 63;
    const int quad = lane >> 4;
    const int mr   = lane & 15;

    __shared__ __align__(16) _Float16 A_lds[MP * KCH];

    const _Float16* inb = in_h + (size_t)b * CIN * (IN * IN);
    float* outp = out + (size_t)blockIdx.z * gridDim.x * COUT * OSZ;

    f32x4 acc[MT][NT];
#pragma unroll
    for (int mt = 0; mt < MT; ++mt)
#pragma unroll
        for (int nt = 0; nt < NT; ++nt) acc[mt][nt] = (f32x4){0.f, 0.f, 0.f, 0.f};

    for (int ch = 0; ch < NCHUNK; ++ch) {
        const int k0 = k00 + ch * KCH;
        __syncthreads();
        for (int slot = tid; slot < SLOTS; slot += 256) {
            int m  = slot % MP;
            int kg = slot / MP;
            bool mok = (m < OSZ);
            int oh = mok ? m / OUT : 0;
            int ow = mok ? m % OUT : 0;
            int kbase = k0 + kg * 8;
            f16x8 av;
#pragma unroll
            for (int j = 0; j < 8; ++j) {
                int k  = kbase + j;
                int ci = k / KK;
                int r  = k % KK;
                int kh = r / Kk, kw = r % Kk;
                _Float16 x = (_Float16)0.f;
                if (mok) x = inb[ci * (IN * IN) + (oh * S + kh) * IN + (ow * S + kw)];
                av[j] = x;
            }
            *(f16x8*)&A_lds[(kg * MP + m) * 8] = av;
        }
        __syncthreads();
        f16x8 wf[KSN][NT];
#pragma unroll
        for (int ks = 0; ks < KSN; ++ks)
#pragma unroll
            for (int nt = 0; nt < NT; ++nt) {
                int co = co0 + (wv * NT + nt) * 16 + mr;
                wf[ks][nt] = *(const f16x8*)&w_h[(size_t)co * KTOT + k0 + ks * 32 + quad * 8];
            }
#pragma unroll
        for (int ks = 0; ks < KSN; ++ks) {
#pragma unroll
            for (int mt = 0; mt < MT; ++mt) {
                f16x8 bv = *(const f16x8*)&A_lds[((ks * 4 + quad) * MP + mt * 16 + mr) * 8];
#pragma unroll
                for (int nt = 0; nt < NT; ++nt)
                    acc[mt][nt] = __builtin_amdgcn_mfma_f32_16x16x32_f16(wf[ks][nt], bv, acc[mt][nt], 0, 0, 0);
            }
        }
    }

#pragma unroll
    for (int mt = 0; mt < MT; ++mt) {
        int sp = mt * 16 + mr;
        if (sp >= OSZ) continue;
#pragma unroll
        for (int nt = 0; nt < NT; ++nt) {
#pragma unroll
            for (int r = 0; r < 4; ++r) {
                int co = co0 + (wv * NT + nt) * 16 + quad * 4 + r;
                outp[((size_t)b * COUT + co) * OSZ + sp] = acc[mt][nt][r];
            }
        }
    }
}

// ---------------------------------------------------------------------------
// sum KSPL split-K partials + bias + ReLU -> f16 out.
// ---------------------------------------------------------------------------
__global__ __launch_bounds__(256) void reduce_bias_relu_f16(
    const float* __restrict__ p, const float* __restrict__ bias,
    _Float16* __restrict__ out, int cout, int osz, int total, int kspl)
{
    for (int i = blockIdx.x * 256 + threadIdx.x; i < total; i += gridDim.x * 256) {
        float s = 0.f;
        for (int ks = 0; ks < kspl; ++ks) s += p[(size_t)ks * total + i];
        int co = (i / osz) % cout;
        out[i] = (_Float16)fmaxf(s + bias[co], 0.f);
    }
}

// ---------------------------------------------------------------------------
// sum KSPL split-K partials + bias + ReLU -> fp32 out.
// ---------------------------------------------------------------------------
__global__ __launch_bounds__(256) void reduce_bias_relu(
    const float* __restrict__ p, const float* __restrict__ bias,
    float* __restrict__ out, int cout, int osz, int total, int kspl)
{
    for (int i = blockIdx.x * 256 + threadIdx.x; i < total; i += gridDim.x * 256) {
        float s = 0.f;
        for (int ks = 0; ks < kspl; ++ks) s += p[(size_t)ks * total + i];
        int co = (i / osz) % cout;
        out[i] = fmaxf(s + bias[co], 0.f);
    }
}

// ---------------------------------------------------------------------------
// fp32 -> f16 cast (weight prep).
// ---------------------------------------------------------------------------
__global__ __launch_bounds__(256) void cast_f16(
    const float* __restrict__ src, _Float16* __restrict__ dst, int n)
{
    for (int i = blockIdx.x * 256 + threadIdx.x; i < n; i += gridDim.x * 256)
        dst[i] = (_Float16)src[i];
}

// ---------------------------------------------------------------------------
// w1 cast with K-pad 75 -> 96 (both branches in one dispatch, grid.y picks).
// ---------------------------------------------------------------------------
__global__ __launch_bounds__(256) void cast_w1_pad(
    const float* __restrict__ s0, _Float16* __restrict__ d0,
    const float* __restrict__ s1, _Float16* __restrict__ d1)
{
    const float* s = blockIdx.y ? s1 : s0;
    _Float16* d = blockIdx.y ? d1 : d0;
    int i = blockIdx.x * 256 + threadIdx.x;
    if (i < 128 * 96) {
        int co = i / 96, k = i % 96;
        d[i] = (k < 75) ? (_Float16)s[co * 75 + k] : (_Float16)0.f;
    }
}

// ---------------------------------------------------------------------------
// FC split-K: partial dot -> atomicAdd into out[b*NO+o] (pre-zeroed).
// ---------------------------------------------------------------------------
__global__ __launch_bounds__(256) void fc_atomic(
    const float* __restrict__ z, const float* __restrict__ fcw,
    float* __restrict__ out, int Kdim, int NO, int KSPL)
{
    const int b = blockIdx.x, o = blockIdx.y, ks = blockIdx.z;
    const int kchunk = Kdim / KSPL;
    const int k0 = ks * kchunk;
    const float* zp = z + (size_t)b * Kdim + k0;
    const float* wp = fcw + (size_t)o * Kdim + k0;
    float s = 0.f;
    for (int k = threadIdx.x; k < kchunk; k += 256) s = fmaf(zp[k], wp[k], s);
    __shared__ float red[4];
    for (int off = 32; off; off >>= 1) s += __shfl_down(s, off, 64);
    if ((threadIdx.x & 63) == 0) red[threadIdx.x >> 6] = s;
    __syncthreads();
    if (threadIdx.x == 0)
        atomicAdd(&out[(size_t)b * NO + o], red[0] + red[1] + red[2] + red[3]);
}

// ---------------------------------------------------------------------------
// m = reshape(|h|,3,3)^T; n = max L1 row norm + 1e-4; msc = m / n.
// ---------------------------------------------------------------------------
__global__ void build_m(const float* __restrict__ h, float* __restrict__ msc)
{
    int b = threadIdx.x;
    if (b < 16) {
        float m[9];
#pragma unroll
        for (int i = 0; i < 3; ++i)
#pragma unroll
            for (int j = 0; j < 3; ++j) m[i * 3 + j] = fabsf(h[b * 9 + j * 3 + i]);
        float n = 0.f;
#pragma unroll
        for (int i = 0; i < 3; ++i) {
            float r = m[i * 3] + m[i * 3 + 1] + m[i * 3 + 2];
            n = fmaxf(n, r);
        }
        n += 1e-4f;
        float inv = 1.f / n;
#pragma unroll
        for (int k = 0; k < 9; ++k) msc[b * 9 + k] = m[k] * inv;
    }
}

// ---------------------------------------------------------------------------
// est[b] = inv(msc[b]) @ |ill[b]|
// ---------------------------------------------------------------------------
__global__ void final_est(const float* __restrict__ msc, const float* __restrict__ ill,
                          float* __restrict__ out)
{
    int bidx = threadIdx.x;
    if (bidx < 16) {
        const float* m = msc + bidx * 9;
        float a = m[0], b = m[1], c = m[2];
        float d = m[3], e = m[4], f = m[5];
        float g = m[6], h = m[7], i = m[8];
        float A = e * i - f * h, B = f * g - d * i, C = d * h - e * g;
        float D = c * h - b * i, E = a * i - c * g, F = b * g - a * h;
        float G = b * f - c * e, H = c * d - a * f, I = a * e - b * d;
        float det = a * A + b * B + c * C;
        float inv_det = 1.f / det;
        float x0 = fabsf(ill[bidx * 3 + 0]);
        float x1 = fabsf(ill[bidx * 3 + 1]);
        float x2 = fabsf(ill[bidx * 3 + 2]);
        out[bidx * 3 + 0] = (A * x0 + D * x1 + G * x2) * inv_det;
        out[bidx * 3 + 1] = (B * x0 + E * x1 + H * x2) * inv_det;
        out[bidx * 3 + 2] = (C * x0 + F * x1 + I * x2) * inv_det;
    }
}

extern "C" void kernel_launch(void* const* d_in, const int* in_sizes, int n_in,
                              void* d_out, int out_size, void* d_ws, size_t ws_size,
                              hipStream_t stream)
{
    (void)in_sizes; (void)n_in; (void)out_size; (void)ws_size;
    const float* image = (const float*)d_in[0];
    const float* su_s  = (const float*)d_in[1];
    const float* sv_s  = (const float*)d_in[2];
    const float* c_s   = (const float*)d_in[3];
    const float* w1_s  = (const float*)d_in[4];
    const float* b1_s  = (const float*)d_in[5];
    const float* w2_s  = (const float*)d_in[6];
    const float* b2_s  = (const float*)d_in[7];
    const float* w3_s  = (const float*)d_in[8];
    const float* b3_s  = (const float*)d_in[9];
    const float* fc_s  = (const float*)d_in[10];
    const float* su_i  = (const float*)d_in[11];
    const float* sv_i  = (const float*)d_in[12];
    const float* c_i   = (const float*)d_in[13];
    const float* w1_i  = (const float*)d_in[14];
    const float* b1_i  = (const float*)d_in[15];
    const float* w2_i  = (const float*)d_in[16];
    const float* b2_i  = (const float*)d_in[17];
    const float* w3_i  = (const float*)d_in[18];
    const float* b3_i  = (const float*)d_in[19];
    const float* fc_i  = (const float*)d_in[20];

    // ---- workspace layout: cumulative pointer arithmetic ONLY (r8 bug:
    // hand-summed mixed float/half offsets overlapped w1h with w3h_i) ----
    float* W     = (float*)d_ws;
    float* hist  = W;                         // 16*3*61*61 = 178608 f
    float* o3    = hist + 178608;             // 16*512*169 = 1384448 f
    float* hd    = o3 + 1384448;              // 144 f
    float* msc   = hd + 144;                  // 144 f
    float* p2    = msc + 144;                 // 4*16*256*196 = 3211264 f
    float* p3    = p2 + 3211264;              // 4*16*512*169 = 5537792 f
    _Float16* o1h   = (_Float16*)(p3 + 5537792);
    _Float16* o2h   = o1h   + 1722368;        // o1h: 16*128*841 halfs
    _Float16* w2h_s = o2h   + 802816;         // o2h: 16*256*196 halfs
    _Float16* w3h_s = w2h_s + 294912;         // w2h: 256*1152 halfs
    _Float16* w2h_i = w3h_s + 524288;         // w3h: 512*1024 halfs
    _Float16* w3h_i = w2h_i + 294912;
    _Float16* w1h_s = w3h_i + 524288;         // after w3h_i's FULL extent
    _Float16* w1h_i = w1h_s + 12288;          // w1h: 128*96 halfs
    // total ~49.7 MB

    const size_t HIST_BYTES = 178608u * sizeof(float);
    const int FCK = 512 * 13 * 13;
    const int O2_TOT = 16 * 256 * 196;
    const int O3_TOT = 16 * 512 * 169;

    // ---- weight prep (f16 casts) ----
    cast_w1_pad<<<dim3(48, 2), 256, 0, stream>>>(w1_s, w1h_s, w1_i, w1h_i);
    cast_f16<<<288, 256, 0, stream>>>(w2_s, w2h_s, 256 * 1152);
    cast_f16<<<512, 256, 0, stream>>>(w3_s, w3h_s, 512 * 1024);
    cast_f16<<<288, 256, 0, stream>>>(w2_i, w2h_i, 256 * 1152);
    cast_f16<<<512, 256, 0, stream>>>(w3_i, w3h_i, 512 * 1024);

    // ================= sensor branch =================
    hipMemsetAsync(hist, 0, HIST_BYTES, stream);
    hipMemsetAsync(hd, 0, 144 * 4, stream);
    hist_mfma<<<dim3(48, HSP), 256, 0, stream>>>(image, su_s, sv_s, c_s, nullptr, hist);
    norm_hist<<<16, 256, 0, stream>>>(hist);
    conv1_mfma<<<dim3(16, 7), 256, 0, stream>>>(hist, w1h_s, b1_s, o1h);
    conv_mfma<128, 256, 3, 2, 29, 14, 128, 4, 96><<<dim3(16, 2, 4), 256, 0, stream>>>(o1h, w2h_s, p2);
    reduce_bias_relu_f16<<<1024, 256, 0, stream>>>(p2, b2_s, o2h, 256, 196, O2_TOT, 4);
    conv_mfma<256, 512, 2, 1, 14, 13, 128, 4, 64><<<dim3(16, 4, 4), 256, 0, stream>>>(o2h, w3h_s, p3);
    reduce_bias_relu<<<1024, 256, 0, stream>>>(p3, b3_s, o3, 512, 169, O3_TOT, 4);
    fc_atomic<<<dim3(16, 9, 8), 256, 0, stream>>>(o3, fc_s, hd, FCK, 9, 8);
    build_m<<<1, 64, 0, stream>>>(hd, msc);

    // ================= illuminant branch =================
    hipMemsetAsync(hist, 0, HIST_BYTES, stream);
    hipMemsetAsync(hd, 0, 144 * 4, stream);
    hist_mfma<<<dim3(48, HSP), 256, 0, stream>>>(image, su_i, sv_i, c_i, msc, hist);
    norm_hist<<<16, 256, 0, stream>>>(hist);
    conv1_mfma<<<dim3(16, 7), 256, 0, stream>>>(hist, w1h_i, b1_i, o1h);
    conv_mfma<128, 256, 3, 2, 29, 14, 128, 4, 96><<<dim3(16, 2, 4), 256, 0, stream>>>(o1h, w2h_i, p2);
    reduce_bias_relu_f16<<<1024, 256, 0, stream>>>(p2, b2_i, o2h, 256, 196, O2_TOT, 4);
    conv_mfma<256, 512, 2, 1, 14, 13, 128, 4, 64><<<dim3(16, 4, 4), 256, 0, stream>>>(o2h, w3h_i, p3);
    reduce_bias_relu<<<1024, 256, 0, stream>>>(p3, b3_i, o3, 512, 169, O3_TOT, 4);
    fc_atomic<<<dim3(16, 3, 8), 256, 0, stream>>>(o3, fc_i, hd, FCK, 3, 8);
    final_est<<<1, 64, 0, stream>>>(msc, hd, (float*)d_out);
}